// Round 1
// baseline (18849.834 us; speedup 1.0000x reference)
//
#include <hip/hip_runtime.h>
#include <cstdint>

#define T_DIM 512
#define B_DIM 64
#define I_DIM 256
#define H_DIM 512

typedef short bf16x8 __attribute__((ext_vector_type(8)));
typedef float f32x4  __attribute__((ext_vector_type(4)));

__device__ __forceinline__ short f2bf(float f) {
  unsigned u = __float_as_uint(f);
  unsigned r = (u + 0x7FFFu + ((u >> 16) & 1u)) >> 16;  // RNE
  return (short)r;
}
__device__ __forceinline__ float bf2f(short s) {
  return __uint_as_float(((unsigned)(unsigned short)s) << 16);
}
__device__ __forceinline__ float sigm(float v) { return 1.0f / (1.0f + __expf(-v)); }
__device__ __forceinline__ float tanh_f(float v) {
  float e = __expf(2.0f * fabsf(v));
  float r = 1.0f - 2.0f / (e + 1.0f);
  return copysignf(r, v);
}

#define WS_CTR_BYTES 4096
#define GRP_STRIDE_SHORTS 65536                 // 131072 bytes per group
#define WS_NEED (WS_CTR_BYTES + 8u * 131072u)   // ~1.05 MB

__global__ void __launch_bounds__(256) init_ws_kernel(unsigned* ws) {
  unsigned n = WS_NEED / 4u;
  for (unsigned i = blockIdx.x * 256u + threadIdx.x; i < n; i += gridDim.x * 256u)
    ws[i] = 0u;
}

// 256 blocks x 256 threads. Group g = blockIdx&7 (dir x batch-tile), 32 blocks/group,
// each block owns 16 output columns (js = blockIdx>>3). One group barrier per step.
__global__ void __launch_bounds__(256, 1) lstm_kernel(
    const float* __restrict__ x, const float* __restrict__ tim,
    const float* __restrict__ Wih_f, const float* __restrict__ Whh_f,
    const float* __restrict__ bias_f, const float* __restrict__ Wd_f,
    const float* __restrict__ bd_f,
    const float* __restrict__ Wih_b, const float* __restrict__ Whh_b,
    const float* __restrict__ bias_b, const float* __restrict__ Wd_b,
    const float* __restrict__ bd_b,
    float* __restrict__ out, char* __restrict__ wsb)
{
  const int g   = blockIdx.x & 7;
  const int js  = blockIdx.x >> 3;        // 0..31 (j-slice)
  const int dir = g & 1;
  const int mt  = g >> 1;                 // batch tile 0..3
  const int b0  = mt * 16;
  const int tid = threadIdx.x;
  const int w   = tid >> 6;               // wave 0..3
  const int l   = tid & 63;
  const int lw  = l & 15;                 // B-frag col / update col
  const int ko  = l >> 4;                 // k-octet selector

  const float* Wih  = dir ? Wih_b  : Wih_f;
  const float* Whh  = dir ? Whh_b  : Whh_f;
  const float* bias = dir ? bias_b : bias_f;
  const float* Wd   = dir ? Wd_b   : Wd_f;
  const float* bd   = dir ? bd_b   : bd_f;

  int* ctr = (int*)wsb + g * 32;          // 128B-separated counters
  short* sbase = (short*)(wsb + WS_CTR_BYTES) + (size_t)g * GRP_STRIDE_SHORTS;
  short* h_hi_g = sbase;                  // [2][16][512] bf16, double-buffered
  short* h_lo_g = sbase + 16384;
  short* c_hi_g = sbase + 32768;
  short* c_lo_g = sbase + 49152;

  __shared__ short xh_hi[16][776];        // [16 batches][768 K + pad8]
  __shared__ short xh_lo[16][776];
  __shared__ float gateL[4][16][24];      // cross-wave gate sums (i,f,g,o)
  __shared__ float csL[16][24];           // cross-wave c_s sum

  // ---- weight preload into registers (hi/lo bf16 split), persists all 512 steps ----
  bf16x8 wgh[4][6], wgl[4][6], wdh[4], wdl[4];
  #pragma unroll
  for (int kk = 0; kk < 6; ++kk) {
    const int kt = w * 6 + kk;            // 24 K-tiles: 0..7 -> W_ih, 8..23 -> W_hh
    const float* wsrc = (kt < 8) ? Wih : Whh;
    const int krow = ((kt < 8) ? kt * 32 : (kt - 8) * 32) + ko * 8;
    #pragma unroll
    for (int g4 = 0; g4 < 4; ++g4) {
      const float* p = wsrc + (size_t)krow * 2048 + g4 * 512 + js * 16 + lw;
      #pragma unroll
      for (int i = 0; i < 8; ++i) {
        float v = p[(size_t)i * 2048];
        short hi = f2bf(v);
        wgh[g4][kk][i] = hi;
        wgl[g4][kk][i] = f2bf(v - bf2f(hi));
      }
    }
  }
  #pragma unroll
  for (int q = 0; q < 4; ++q) {
    const int krow = (w * 4 + q) * 32 + ko * 8;   // 16 K-tiles of W_d split 4/wave
    const float* p = Wd + (size_t)krow * 512 + js * 16 + lw;
    #pragma unroll
    for (int i = 0; i < 8; ++i) {
      float v = p[(size_t)i * 512];
      short hi = f2bf(v);
      wdh[q][i] = hi;
      wdl[q][i] = f2bf(v - bf2f(hi));
    }
  }

  // update-phase mapping: thread owns (batch ub, column uj)
  const int ub = tid >> 4;
  const int uj = tid & 15;
  const int jglob = js * 16 + uj;
  const float bs_i = bias[jglob];
  const float bs_f = bias[512 + jglob];
  const float bs_g = bias[1024 + jglob];
  const float bs_o = bias[1536 + jglob];
  const float bs_d = bd[jglob];
  float c_reg = 0.0f;                     // private fp32 cell state

  #pragma unroll
  for (int g4 = 0; g4 < 4; ++g4) gateL[g4][ub][uj] = 0.0f;
  csL[ub][uj] = 0.0f;
  __syncthreads();

  const int srow = tid & 15;              // staging row
  const int sseg = tid >> 4;              // staging segment
  const int arow = lw;                    // A-frag row (batch)

  for (int t = 0; t < T_DIM; ++t) {
    const int tsrc = dir ? (T_DIM - 1 - t) : t;
    const int buf = t & 1;
    const int nbuf = buf ^ 1;

    // ---- S1: stage xh tile (x converted fp32->hi/lo on the fly; h from global bf16) ----
    {
      const float* xp = x + ((size_t)tsrc * B_DIM + b0 + srow) * I_DIM + sseg * 16;
      #pragma unroll
      for (int c4 = 0; c4 < 2; ++c4) {
        bf16x8 vh, vl;
        #pragma unroll
        for (int i = 0; i < 8; ++i) {
          float v = xp[c4 * 8 + i];
          short hi = f2bf(v);
          vh[i] = hi;
          vl[i] = f2bf(v - bf2f(hi));
        }
        *(bf16x8*)&xh_hi[srow][sseg * 16 + c4 * 8] = vh;
        *(bf16x8*)&xh_lo[srow][sseg * 16 + c4 * 8] = vl;
      }
      const short* hph = h_hi_g + buf * 8192 + srow * 512 + sseg * 32;
      const short* hpl = h_lo_g + buf * 8192 + srow * 512 + sseg * 32;
      #pragma unroll
      for (int o = 0; o < 4; ++o) {
        *(bf16x8*)&xh_hi[srow][256 + sseg * 32 + o * 8] = *(const bf16x8*)(hph + o * 8);
        *(bf16x8*)&xh_lo[srow][256 + sseg * 32 + o * 8] = *(const bf16x8*)(hpl + o * 8);
      }
    }
    __syncthreads();

    // ---- S2: MFMA (split-bf16: hi*hi + lo*hi + hi*lo) ----
    {
      f32x4 ag[4][2]; f32x4 ac[2];
      #pragma unroll
      for (int g4 = 0; g4 < 4; ++g4) { ag[g4][0] = (f32x4)0.0f; ag[g4][1] = (f32x4)0.0f; }
      ac[0] = (f32x4)0.0f; ac[1] = (f32x4)0.0f;

      #pragma unroll
      for (int kk = 0; kk < 6; ++kk) {
        const int col = (w * 6 + kk) * 32 + ko * 8;
        bf16x8 ahi = *(const bf16x8*)&xh_hi[arow][col];
        bf16x8 alo = *(const bf16x8*)&xh_lo[arow][col];
        #pragma unroll
        for (int g4 = 0; g4 < 4; ++g4) {
          f32x4 acc = ag[g4][kk & 1];
          acc = __builtin_amdgcn_mfma_f32_16x16x32_bf16(ahi, wgh[g4][kk], acc, 0, 0, 0);
          acc = __builtin_amdgcn_mfma_f32_16x16x32_bf16(alo, wgh[g4][kk], acc, 0, 0, 0);
          acc = __builtin_amdgcn_mfma_f32_16x16x32_bf16(ahi, wgl[g4][kk], acc, 0, 0, 0);
          ag[g4][kk & 1] = acc;
        }
      }
      {
        const short* cbh = c_hi_g + buf * 8192 + arow * 512 + w * 128 + ko * 8;
        const short* cbl = c_lo_g + buf * 8192 + arow * 512 + w * 128 + ko * 8;
        #pragma unroll
        for (int q = 0; q < 4; ++q) {
          bf16x8 chi = *(const bf16x8*)(cbh + q * 32);
          bf16x8 clo = *(const bf16x8*)(cbl + q * 32);
          f32x4 acc = ac[q & 1];
          acc = __builtin_amdgcn_mfma_f32_16x16x32_bf16(chi, wdh[q], acc, 0, 0, 0);
          acc = __builtin_amdgcn_mfma_f32_16x16x32_bf16(clo, wdh[q], acc, 0, 0, 0);
          acc = __builtin_amdgcn_mfma_f32_16x16x32_bf16(chi, wdl[q], acc, 0, 0, 0);
          ac[q & 1] = acc;
        }
      }
      // cross-wave partial exchange (each wave holds a K-slice of every gate)
      #pragma unroll
      for (int g4 = 0; g4 < 4; ++g4) {
        f32x4 s = ag[g4][0] + ag[g4][1];
        #pragma unroll
        for (int r = 0; r < 4; ++r)
          atomicAdd(&gateL[g4][ko * 4 + r][lw], s[r]);
      }
      {
        f32x4 s = ac[0] + ac[1];
        #pragma unroll
        for (int r = 0; r < 4; ++r)
          atomicAdd(&csL[ko * 4 + r][lw], s[r]);
      }
    }
    __syncthreads();

    // ---- S3: elementwise update (thread owns (ub, uj)) ----
    {
      float gi = gateL[0][ub][uj] + bs_i;
      float gf = gateL[1][ub][uj] + bs_f;
      float gg = gateL[2][ub][uj] + bs_g;
      float go = gateL[3][ub][uj] + bs_o;
      float csv = csL[ub][uj] + bs_d;
      gateL[0][ub][uj] = 0.0f; gateL[1][ub][uj] = 0.0f;
      gateL[2][ub][uj] = 0.0f; gateL[3][ub][uj] = 0.0f;
      csL[ub][uj] = 0.0f;

      float c_s = tanh_f(csv);
      float tt = tim[(size_t)tsrc * B_DIM + b0 + ub];
      float dinv = 1.0f / __logf(2.718281828459045f + tt);
      float c_adj = c_reg - c_s + c_s * dinv;
      float iv = sigm(gi);
      float fv = sigm(gf);
      float ov = sigm(go);
      float gv = tanh_f(gg);
      float c_new = fv * c_adj + iv * gv;
      float h_new = ov * tanh_f(c_new);
      c_reg = c_new;

      short hh = f2bf(h_new), hl2 = f2bf(h_new - bf2f(hh));
      short ch = f2bf(c_new), cl2 = f2bf(c_new - bf2f(ch));
      const int si = nbuf * 8192 + ub * 512 + jglob;
      h_hi_g[si] = hh; h_lo_g[si] = hl2;
      c_hi_g[si] = ch; c_lo_g[si] = cl2;
      out[((size_t)tsrc * B_DIM + b0 + ub) * 1024 + dir * 512 + jglob] = h_new;
    }

    // ---- S4: group barrier (32 blocks, monotonic counter) ----
    __threadfence();
    __syncthreads();
    if (tid == 0) {
      atomicAdd(ctr, 1);
      const int target = 32 * (t + 1);
      while (__hip_atomic_load(ctr, __ATOMIC_ACQUIRE, __HIP_MEMORY_SCOPE_AGENT) < target)
        __builtin_amdgcn_s_sleep(2);
    }
    __syncthreads();
  }
}

extern "C" void kernel_launch(void* const* d_in, const int* in_sizes, int n_in,
                              void* d_out, int out_size, void* d_ws, size_t ws_size,
                              hipStream_t stream) {
  (void)in_sizes; (void)n_in; (void)out_size;
  if (ws_size < (size_t)WS_NEED) return;  // failure signature: ws too small

  const float* x     = (const float*)d_in[0];
  const float* tim   = (const float*)d_in[1];
  const float* Wih_f = (const float*)d_in[2];
  const float* Whh_f = (const float*)d_in[3];
  const float* b_f   = (const float*)d_in[4];
  const float* Wd_f  = (const float*)d_in[5];
  const float* bd_f  = (const float*)d_in[6];
  const float* Wih_b = (const float*)d_in[7];
  const float* Whh_b = (const float*)d_in[8];
  const float* b_b   = (const float*)d_in[9];
  const float* Wd_b  = (const float*)d_in[10];
  const float* bd_b  = (const float*)d_in[11];
  float* out = (float*)d_out;
  char* ws = (char*)d_ws;

  hipLaunchKernelGGL(init_ws_kernel, dim3(64), dim3(256), 0, stream, (unsigned*)ws);
  hipLaunchKernelGGL(lstm_kernel, dim3(256), dim3(256), 0, stream,
                     x, tim, Wih_f, Whh_f, b_f, Wd_f, bd_f,
                     Wih_b, Whh_b, b_b, Wd_b, bd_b, out, ws);
}

// Round 2
// 7053.155 us; speedup vs baseline: 2.6725x; 2.6725x over previous
//
#include <hip/hip_runtime.h>
#include <cstdint>

#define T_DIM 512
#define B_DIM 64
#define I_DIM 256
#define H_DIM 512

typedef short bf16x8 __attribute__((ext_vector_type(8)));
typedef float f32x4  __attribute__((ext_vector_type(4)));
typedef unsigned int u32x4 __attribute__((ext_vector_type(4)));

__device__ __forceinline__ short f2bf(float f) {
  unsigned u = __float_as_uint(f);
  unsigned r = (u + 0x7FFFu + ((u >> 16) & 1u)) >> 16;  // RNE
  return (short)r;
}
__device__ __forceinline__ float bf2f(short s) {
  return __uint_as_float(((unsigned)(unsigned short)s) << 16);
}
__device__ __forceinline__ float sigm(float v) { return 1.0f / (1.0f + __expf(-v)); }
__device__ __forceinline__ float tanh_f(float v) {
  float e = __expf(2.0f * fabsf(v));
  float r = 1.0f - 2.0f / (e + 1.0f);
  return copysignf(r, v);
}

#define WS_FLAGS_BYTES 4096
#define GRP_BYTES 131072u
#define WS_NEED (WS_FLAGS_BYTES + 8u * GRP_BYTES)   // ~1.05 MB

__global__ void __launch_bounds__(256) init_ws_kernel(unsigned* ws) {
  unsigned n = WS_NEED / 4u;
  for (unsigned i = blockIdx.x * 256u + threadIdx.x; i < n; i += gridDim.x * 256u)
    ws[i] = 0u;
}

// 256 blocks x 256 threads. Group g = blockIdx&7 (dir x batch-tile), 32 blocks/group,
// each block owns 16 output columns (js = blockIdx>>3).
// Sync: per-block release flag + parallel acquire polling (no contended atomics).
// MFMA A/C fragments loaded DIRECTLY from global (per-wave K-slices are disjoint).
__global__ void __launch_bounds__(256, 1) lstm_kernel(
    const float* __restrict__ x, const float* __restrict__ tim,
    const float* __restrict__ Wih_f, const float* __restrict__ Whh_f,
    const float* __restrict__ bias_f, const float* __restrict__ Wd_f,
    const float* __restrict__ bd_f,
    const float* __restrict__ Wih_b, const float* __restrict__ Whh_b,
    const float* __restrict__ bias_b, const float* __restrict__ Wd_b,
    const float* __restrict__ bd_b,
    float* __restrict__ out, char* __restrict__ wsb)
{
  const int g   = blockIdx.x & 7;
  const int js  = blockIdx.x >> 3;        // 0..31 (j-slice)
  const int dir = g & 1;
  const int mt  = g >> 1;                 // batch tile 0..3
  const int b0  = mt * 16;
  const int tid = threadIdx.x;
  const int w   = tid >> 6;               // wave 0..3
  const int l   = tid & 63;
  const int lw  = l & 15;                 // A-frag row (batch) / B-frag col
  const int ko  = l >> 4;                 // k-octet selector

  const float* Wih  = dir ? Wih_b  : Wih_f;
  const float* Whh  = dir ? Whh_b  : Whh_f;
  const float* bias = dir ? bias_b : bias_f;
  const float* Wd   = dir ? Wd_b   : Wd_f;
  const float* bd   = dir ? bd_b   : bd_f;

  int* flags = (int*)wsb + g * 32;                         // 128B per group
  unsigned* gbase = (unsigned*)(wsb + WS_FLAGS_BYTES) + (size_t)g * (GRP_BYTES / 4);
  unsigned* h_pack = gbase;                                // [2][16][512] uint (hi<<16|lo)
  unsigned* c_pack = gbase + 16384;                        // [2][16][512] uint

  __shared__ float red[4][5][16][18];     // [wave][i,f,g,o,cs][batch][col+pad]

  // ---- weight preload into registers (hi/lo bf16 split), persists all 512 steps ----
  bf16x8 wgh[4][6], wgl[4][6], wdh[4], wdl[4];
  #pragma unroll
  for (int kk = 0; kk < 6; ++kk) {
    const int kt = w * 6 + kk;            // 24 K-tiles: 0..7 -> W_ih, 8..23 -> W_hh
    const float* wsrc = (kt < 8) ? Wih : Whh;
    const int krow = ((kt < 8) ? kt * 32 : (kt - 8) * 32) + ko * 8;
    #pragma unroll
    for (int g4 = 0; g4 < 4; ++g4) {
      const float* p = wsrc + (size_t)krow * 2048 + g4 * 512 + js * 16 + lw;
      #pragma unroll
      for (int i = 0; i < 8; ++i) {
        float v = p[(size_t)i * 2048];
        short hi = f2bf(v);
        wgh[g4][kk][i] = hi;
        wgl[g4][kk][i] = f2bf(v - bf2f(hi));
      }
    }
  }
  #pragma unroll
  for (int q = 0; q < 4; ++q) {
    const int krow = (w * 4 + q) * 32 + ko * 8;   // 16 K-tiles of W_d split 4/wave
    const float* p = Wd + (size_t)krow * 512 + js * 16 + lw;
    #pragma unroll
    for (int i = 0; i < 8; ++i) {
      float v = p[(size_t)i * 512];
      short hi = f2bf(v);
      wdh[q][i] = hi;
      wdl[q][i] = f2bf(v - bf2f(hi));
    }
  }

  // update-phase mapping: thread owns (batch ub, column uj)
  const int ub = tid >> 4;
  const int uj = tid & 15;
  const int jglob = js * 16 + uj;
  const float bs_i = bias[jglob];
  const float bs_f = bias[512 + jglob];
  const float bs_g = bias[1024 + jglob];
  const float bs_o = bias[1536 + jglob];
  const float bs_d = bd[jglob];
  float c_reg = 0.0f;                     // private fp32 cell state

  for (int t = 0; t < T_DIM; ++t) {
    const int tsrc = dir ? (T_DIM - 1 - t) : t;
    const int buf = t & 1;
    const int nbuf = buf ^ 1;

    // ---- W0: wait for all 32 producer blocks to finish step t-1 ----
    if (t > 0) {
      if (tid < 32) {
        while (__hip_atomic_load(&flags[tid], __ATOMIC_RELAXED, __HIP_MEMORY_SCOPE_AGENT) < t) { }
        (void)__hip_atomic_load(&flags[tid], __ATOMIC_ACQUIRE, __HIP_MEMORY_SCOPE_AGENT);
      }
      __syncthreads();
    }

    // ---- S1: direct fragment loads (x: fp32->hi/lo; h/c: packed uint) ----
    float tt = tim[(size_t)tsrc * B_DIM + b0 + ub];   // issue early
    bf16x8 ahi[6], alo[6], chi[4], clo[4];
    #pragma unroll
    for (int kk = 0; kk < 6; ++kk) {
      const int kt = w * 6 + kk;
      if (kt < 8) {
        const float* xp = x + ((size_t)tsrc * B_DIM + b0 + lw) * I_DIM + kt * 32 + ko * 8;
        f32x4 v0 = *(const f32x4*)xp;
        f32x4 v1 = *(const f32x4*)(xp + 4);
        bf16x8 vh, vl;
        #pragma unroll
        for (int i = 0; i < 4; ++i) {
          short h0 = f2bf(v0[i]); vh[i] = h0;     vl[i] = f2bf(v0[i] - bf2f(h0));
          short h1 = f2bf(v1[i]); vh[4 + i] = h1; vl[4 + i] = f2bf(v1[i] - bf2f(h1));
        }
        ahi[kk] = vh; alo[kk] = vl;
      } else {
        const unsigned* hp = h_pack + (size_t)buf * 8192 + lw * 512 + (kt - 8) * 32 + ko * 8;
        u32x4 u0 = *(const u32x4*)hp;
        u32x4 u1 = *(const u32x4*)(hp + 4);
        bf16x8 vh, vl;
        #pragma unroll
        for (int i = 0; i < 4; ++i) {
          vh[i]     = (short)(u0[i] >> 16); vl[i]     = (short)(u0[i] & 0xffffu);
          vh[4 + i] = (short)(u1[i] >> 16); vl[4 + i] = (short)(u1[i] & 0xffffu);
        }
        ahi[kk] = vh; alo[kk] = vl;
      }
    }
    #pragma unroll
    for (int q = 0; q < 4; ++q) {
      const unsigned* cp = c_pack + (size_t)buf * 8192 + lw * 512 + (w * 4 + q) * 32 + ko * 8;
      u32x4 u0 = *(const u32x4*)cp;
      u32x4 u1 = *(const u32x4*)(cp + 4);
      bf16x8 vh, vl;
      #pragma unroll
      for (int i = 0; i < 4; ++i) {
        vh[i]     = (short)(u0[i] >> 16); vl[i]     = (short)(u0[i] & 0xffffu);
        vh[4 + i] = (short)(u1[i] >> 16); vl[4 + i] = (short)(u1[i] & 0xffffu);
      }
      chi[q] = vh; clo[q] = vl;
    }

    // ---- S2: MFMA (split-bf16: hi*hi + lo*hi + hi*lo) ----
    f32x4 ag[4][2]; f32x4 ac[2];
    #pragma unroll
    for (int g4 = 0; g4 < 4; ++g4) { ag[g4][0] = (f32x4)0.0f; ag[g4][1] = (f32x4)0.0f; }
    ac[0] = (f32x4)0.0f; ac[1] = (f32x4)0.0f;

    #pragma unroll
    for (int kk = 0; kk < 6; ++kk) {
      #pragma unroll
      for (int g4 = 0; g4 < 4; ++g4) {
        f32x4 acc = ag[g4][kk & 1];
        acc = __builtin_amdgcn_mfma_f32_16x16x32_bf16(ahi[kk], wgh[g4][kk], acc, 0, 0, 0);
        acc = __builtin_amdgcn_mfma_f32_16x16x32_bf16(alo[kk], wgh[g4][kk], acc, 0, 0, 0);
        acc = __builtin_amdgcn_mfma_f32_16x16x32_bf16(ahi[kk], wgl[g4][kk], acc, 0, 0, 0);
        ag[g4][kk & 1] = acc;
      }
    }
    #pragma unroll
    for (int q = 0; q < 4; ++q) {
      f32x4 acc = ac[q & 1];
      acc = __builtin_amdgcn_mfma_f32_16x16x32_bf16(chi[q], wdh[q], acc, 0, 0, 0);
      acc = __builtin_amdgcn_mfma_f32_16x16x32_bf16(clo[q], wdh[q], acc, 0, 0, 0);
      acc = __builtin_amdgcn_mfma_f32_16x16x32_bf16(chi[q], wdl[q], acc, 0, 0, 0);
      ac[q & 1] = acc;
    }

    // ---- S2b: deterministic cross-wave reduce via LDS (pad 18 -> <=2-way banks) ----
    #pragma unroll
    for (int g4 = 0; g4 < 4; ++g4) {
      f32x4 s = ag[g4][0] + ag[g4][1];
      #pragma unroll
      for (int r = 0; r < 4; ++r) red[w][g4][ko * 4 + r][lw] = s[r];
    }
    {
      f32x4 s = ac[0] + ac[1];
      #pragma unroll
      for (int r = 0; r < 4; ++r) red[w][4][ko * 4 + r][lw] = s[r];
    }
    __syncthreads();

    // ---- S3: elementwise update (thread owns (ub, uj)) ----
    {
      float gi = red[0][0][ub][uj] + red[1][0][ub][uj] + red[2][0][ub][uj] + red[3][0][ub][uj] + bs_i;
      float gf = red[0][1][ub][uj] + red[1][1][ub][uj] + red[2][1][ub][uj] + red[3][1][ub][uj] + bs_f;
      float gg = red[0][2][ub][uj] + red[1][2][ub][uj] + red[2][2][ub][uj] + red[3][2][ub][uj] + bs_g;
      float go = red[0][3][ub][uj] + red[1][3][ub][uj] + red[2][3][ub][uj] + red[3][3][ub][uj] + bs_o;
      float csv = red[0][4][ub][uj] + red[1][4][ub][uj] + red[2][4][ub][uj] + red[3][4][ub][uj] + bs_d;

      float c_s = tanh_f(csv);
      float dinv = 1.0f / __logf(2.718281828459045f + tt);
      float c_adj = c_reg - c_s + c_s * dinv;
      float iv = sigm(gi);
      float fv = sigm(gf);
      float ov = sigm(go);
      float gv = tanh_f(gg);
      float c_new = fv * c_adj + iv * gv;
      float h_new = ov * tanh_f(c_new);
      c_reg = c_new;

      short hh = f2bf(h_new), hl2 = f2bf(h_new - bf2f(hh));
      short ch = f2bf(c_new), cl2 = f2bf(c_new - bf2f(ch));
      const int si = nbuf * 8192 + ub * 512 + jglob;
      h_pack[si] = ((unsigned)(unsigned short)hh << 16) | (unsigned)(unsigned short)hl2;
      c_pack[si] = ((unsigned)(unsigned short)ch << 16) | (unsigned)(unsigned short)cl2;
      out[((size_t)tsrc * B_DIM + b0 + ub) * 1024 + dir * 512 + jglob] = h_new;
    }

    // ---- S4: publish (syncthreads drains all waves' stores, then one release flag) ----
    __syncthreads();
    if (tid == 0)
      __hip_atomic_store(&flags[js], t + 1, __ATOMIC_RELEASE, __HIP_MEMORY_SCOPE_AGENT);
  }
}

extern "C" void kernel_launch(void* const* d_in, const int* in_sizes, int n_in,
                              void* d_out, int out_size, void* d_ws, size_t ws_size,
                              hipStream_t stream) {
  (void)in_sizes; (void)n_in; (void)out_size;
  if (ws_size < (size_t)WS_NEED) return;  // failure signature: ws too small

  const float* x     = (const float*)d_in[0];
  const float* tim   = (const float*)d_in[1];
  const float* Wih_f = (const float*)d_in[2];
  const float* Whh_f = (const float*)d_in[3];
  const float* b_f   = (const float*)d_in[4];
  const float* Wd_f  = (const float*)d_in[5];
  const float* bd_f  = (const float*)d_in[6];
  const float* Wih_b = (const float*)d_in[7];
  const float* Whh_b = (const float*)d_in[8];
  const float* b_b   = (const float*)d_in[9];
  const float* Wd_b  = (const float*)d_in[10];
  const float* bd_b  = (const float*)d_in[11];
  float* out = (float*)d_out;
  char* ws = (char*)d_ws;

  hipLaunchKernelGGL(init_ws_kernel, dim3(64), dim3(256), 0, stream, (unsigned*)ws);
  hipLaunchKernelGGL(lstm_kernel, dim3(256), dim3(256), 0, stream,
                     x, tim, Wih_f, Whh_f, b_f, Wd_f, bd_f,
                     Wih_b, Whh_b, b_b, Wd_b, bd_b, out, ws);
}

// Round 3
// 2646.283 us; speedup vs baseline: 7.1231x; 2.6653x over previous
//
#include <hip/hip_runtime.h>
#include <cstdint>

#define T_DIM 512
#define B_DIM 64
#define I_DIM 256
#define H_DIM 512

typedef short bf16x8 __attribute__((ext_vector_type(8)));
typedef float f32x4  __attribute__((ext_vector_type(4)));
typedef unsigned int u32x4 __attribute__((ext_vector_type(4)));
typedef unsigned int u32x2 __attribute__((ext_vector_type(2)));

union BF8U { bf16x8 v; u32x4 u; };

__device__ __forceinline__ short f2bf(float f) {
  unsigned u = __float_as_uint(f);
  unsigned r = (u + 0x7FFFu + ((u >> 16) & 1u)) >> 16;  // RNE
  return (short)r;
}
__device__ __forceinline__ float bf2f(short s) {
  return __uint_as_float(((unsigned)(unsigned short)s) << 16);
}
__device__ __forceinline__ float sigm(float v) { return 1.0f / (1.0f + __expf(-v)); }
__device__ __forceinline__ float tanh_f(float v) {
  float e = __expf(2.0f * fabsf(v));
  float r = 1.0f - 2.0f / (e + 1.0f);
  return copysignf(r, v);
}

#define WS_FLAGS_BYTES 4096
#define GRP_BYTES 131072u                        // state: 2 bufs x 16 batch x 512 k x 8B
#define WS_NEED (WS_FLAGS_BYTES + 8u * GRP_BYTES)

// init with COHERENT stores so no stale dirty zero-lines can later clobber L3.
__global__ void __launch_bounds__(256) init_ws_kernel(unsigned* ws) {
  unsigned n = WS_NEED / 4u;
  for (unsigned i = blockIdx.x * 256u + threadIdx.x; i < n; i += gridDim.x * 256u)
    __hip_atomic_store(&ws[i], 0u, __ATOMIC_RELAXED, __HIP_MEMORY_SCOPE_AGENT);
}

// 256 blocks x 256 threads. Group g = blockIdx&7 (dir x batch-tile), 32 blocks/group,
// block owns 16 output columns (js). Cross-block state via sc0|sc1 coherence-point
// accesses ONLY (no buffer_inv / buffer_wbl2 cache maintenance anywhere).
// Wave w owns k-slices: x k=[w*64,w*64+64), h/c k=[w*128,w*128+128).
__global__ void __launch_bounds__(256, 1) lstm_kernel(
    const float* __restrict__ x, const float* __restrict__ tim,
    const float* __restrict__ Wih_f, const float* __restrict__ Whh_f,
    const float* __restrict__ bias_f, const float* __restrict__ Wd_f,
    const float* __restrict__ bd_f,
    const float* __restrict__ Wih_b, const float* __restrict__ Whh_b,
    const float* __restrict__ bias_b, const float* __restrict__ Wd_b,
    const float* __restrict__ bd_b,
    float* __restrict__ out, char* __restrict__ wsb)
{
  const int g   = blockIdx.x & 7;
  const int js  = blockIdx.x >> 3;        // 0..31 (j-slice)
  const int dir = g & 1;
  const int mt  = g >> 1;                 // batch tile 0..3
  const int b0  = mt * 16;
  const int tid = threadIdx.x;
  const int w   = tid >> 6;               // wave 0..3
  const int l   = tid & 63;
  const int lw  = l & 15;                 // A-frag row (batch) / B-frag col
  const int ko  = l >> 4;                 // k-octet selector

  const float* Wih  = dir ? Wih_b  : Wih_f;
  const float* Whh  = dir ? Whh_b  : Whh_f;
  const float* bias = dir ? bias_b : bias_f;
  const float* Wd   = dir ? Wd_b   : Wd_f;
  const float* bd   = dir ? bd_b   : bd_f;

  int* flags = (int*)wsb + g * 32;                              // 128B per group
  unsigned* state = (unsigned*)(wsb + WS_FLAGS_BYTES) + (size_t)g * (GRP_BYTES / 4);
  // state layout: uint2[buf][batch][k] = (h_hi<<16|h_lo , c_hi<<16|c_lo)

  __shared__ float red[4][5][16][18];     // [wave][i,f,g,o,cs][batch][col+pad]

  // ---- weight preload (hi/lo bf16 split), persists all 512 steps ----
  bf16x8 wxh[4][2], wxl[4][2];            // W_ih slice: [gate][xi]
  bf16x8 whh[4][4], whl[4][4];            // W_hh slice: [gate][q]
  bf16x8 wdh[4],    wdl[4];               // W_d  slice: [q]
  #pragma unroll
  for (int xi = 0; xi < 2; ++xi) {
    const int krow = (w * 2 + xi) * 32 + ko * 8;
    #pragma unroll
    for (int g4 = 0; g4 < 4; ++g4) {
      const float* p = Wih + (size_t)krow * 2048 + g4 * 512 + js * 16 + lw;
      #pragma unroll
      for (int i = 0; i < 8; ++i) {
        float v = p[(size_t)i * 2048];
        short hi = f2bf(v);
        wxh[g4][xi][i] = hi;
        wxl[g4][xi][i] = f2bf(v - bf2f(hi));
      }
    }
  }
  #pragma unroll
  for (int q = 0; q < 4; ++q) {
    const int krow = w * 128 + q * 32 + ko * 8;
    #pragma unroll
    for (int g4 = 0; g4 < 4; ++g4) {
      const float* p = Whh + (size_t)krow * 2048 + g4 * 512 + js * 16 + lw;
      #pragma unroll
      for (int i = 0; i < 8; ++i) {
        float v = p[(size_t)i * 2048];
        short hi = f2bf(v);
        whh[g4][q][i] = hi;
        whl[g4][q][i] = f2bf(v - bf2f(hi));
      }
    }
    const float* p2 = Wd + (size_t)krow * 512 + js * 16 + lw;
    #pragma unroll
    for (int i = 0; i < 8; ++i) {
      float v = p2[(size_t)i * 512];
      short hi = f2bf(v);
      wdh[q][i] = hi;
      wdl[q][i] = f2bf(v - bf2f(hi));
    }
  }

  // update-phase mapping: thread owns (batch ub, column uj)
  const int ub = tid >> 4;
  const int uj = tid & 15;
  const int jglob = js * 16 + uj;
  const float bs_i = bias[jglob];
  const float bs_f = bias[512 + jglob];
  const float bs_g = bias[1024 + jglob];
  const float bs_o = bias[1536 + jglob];
  const float bs_d = bd[jglob];
  float c_reg = 0.0f;

  for (int t = 0; t < T_DIM; ++t) {
    const int tsrc = dir ? (T_DIM - 1 - t) : t;
    const int buf = t & 1;
    const int nbuf = buf ^ 1;

    // ---- X phase (independent of t-1 state; runs while others finish) ----
    f32x4 ag[4][2]; f32x4 ac[2];
    #pragma unroll
    for (int g4 = 0; g4 < 4; ++g4) { ag[g4][0] = (f32x4)0.0f; ag[g4][1] = (f32x4)0.0f; }
    ac[0] = (f32x4)0.0f; ac[1] = (f32x4)0.0f;

    float tt = tim[(size_t)tsrc * B_DIM + b0 + ub];   // early plain load

    bf16x8 axh[2], axl[2];
    #pragma unroll
    for (int xi = 0; xi < 2; ++xi) {
      const float* xp = x + ((size_t)tsrc * B_DIM + b0 + lw) * I_DIM + (w * 2 + xi) * 32 + ko * 8;
      f32x4 v0 = *(const f32x4*)xp;
      f32x4 v1 = *(const f32x4*)(xp + 4);
      bf16x8 vh, vl;
      #pragma unroll
      for (int i = 0; i < 4; ++i) {
        short h0 = f2bf(v0[i]); vh[i] = h0;     vl[i] = f2bf(v0[i] - bf2f(h0));
        short h1 = f2bf(v1[i]); vh[4 + i] = h1; vl[4 + i] = f2bf(v1[i] - bf2f(h1));
      }
      axh[xi] = vh; axl[xi] = vl;
    }
    #pragma unroll
    for (int xi = 0; xi < 2; ++xi) {
      #pragma unroll
      for (int g4 = 0; g4 < 4; ++g4) {
        f32x4 acc = ag[g4][xi];
        acc = __builtin_amdgcn_mfma_f32_16x16x32_bf16(axh[xi], wxh[g4][xi], acc, 0, 0, 0);
        acc = __builtin_amdgcn_mfma_f32_16x16x32_bf16(axl[xi], wxh[g4][xi], acc, 0, 0, 0);
        acc = __builtin_amdgcn_mfma_f32_16x16x32_bf16(axh[xi], wxl[g4][xi], acc, 0, 0, 0);
        ag[g4][xi] = acc;
      }
    }

    // ---- W0: per-wave poll of all 32 producer flags (relaxed, no cache ops) ----
    if (t > 0) {
      if (l < 32) {
        const int* fl = &flags[l];
        while (__hip_atomic_load(fl, __ATOMIC_RELAXED, __HIP_MEMORY_SCOPE_AGENT) < t) { }
      }
      __builtin_amdgcn_sched_barrier(0);
      asm volatile("" ::: "memory");
    }

    // ---- S1: coherent state loads (h,c interleaved uint2), issue all then one wait ----
    u32x4 rr[4][4];
    #pragma unroll
    for (int q = 0; q < 4; ++q) {
      const unsigned* sp = state + 2u * ((size_t)buf * 8192 + (size_t)lw * 512 + w * 128 + q * 32 + ko * 8);
      asm volatile(
          "global_load_dwordx4 %0, %4, off sc0 sc1\n\t"
          "global_load_dwordx4 %1, %4, off offset:16 sc0 sc1\n\t"
          "global_load_dwordx4 %2, %4, off offset:32 sc0 sc1\n\t"
          "global_load_dwordx4 %3, %4, off offset:48 sc0 sc1"
          : "=v"(rr[q][0]), "=v"(rr[q][1]), "=v"(rr[q][2]), "=v"(rr[q][3])
          : "v"(sp) : "memory");
    }
    asm volatile("s_waitcnt vmcnt(0)" ::: "memory");
    __builtin_amdgcn_sched_barrier(0);

    // ---- S2: unpack via v_perm + h/c MFMAs ----
    #pragma unroll
    for (int q = 0; q < 4; ++q) {
      BF8U hh_, hl_, ch_, cl_;
      #pragma unroll
      for (int j = 0; j < 4; ++j) {
        unsigned hw0 = rr[q][j][0], cw0 = rr[q][j][1];
        unsigned hw1 = rr[q][j][2], cw1 = rr[q][j][3];
        hh_.u[j] = __builtin_amdgcn_perm(hw1, hw0, 0x07060302u);
        hl_.u[j] = __builtin_amdgcn_perm(hw1, hw0, 0x05040100u);
        ch_.u[j] = __builtin_amdgcn_perm(cw1, cw0, 0x07060302u);
        cl_.u[j] = __builtin_amdgcn_perm(cw1, cw0, 0x05040100u);
      }
      #pragma unroll
      for (int g4 = 0; g4 < 4; ++g4) {
        f32x4 acc = ag[g4][q & 1];
        acc = __builtin_amdgcn_mfma_f32_16x16x32_bf16(hh_.v, whh[g4][q], acc, 0, 0, 0);
        acc = __builtin_amdgcn_mfma_f32_16x16x32_bf16(hl_.v, whh[g4][q], acc, 0, 0, 0);
        acc = __builtin_amdgcn_mfma_f32_16x16x32_bf16(hh_.v, whl[g4][q], acc, 0, 0, 0);
        ag[g4][q & 1] = acc;
      }
      f32x4 a2 = ac[q & 1];
      a2 = __builtin_amdgcn_mfma_f32_16x16x32_bf16(ch_.v, wdh[q], a2, 0, 0, 0);
      a2 = __builtin_amdgcn_mfma_f32_16x16x32_bf16(cl_.v, wdh[q], a2, 0, 0, 0);
      a2 = __builtin_amdgcn_mfma_f32_16x16x32_bf16(ch_.v, wdl[q], a2, 0, 0, 0);
      ac[q & 1] = a2;
    }

    // ---- S2b: deterministic cross-wave reduce via LDS ----
    #pragma unroll
    for (int g4 = 0; g4 < 4; ++g4) {
      f32x4 s = ag[g4][0] + ag[g4][1];
      #pragma unroll
      for (int r = 0; r < 4; ++r) red[w][g4][ko * 4 + r][lw] = s[r];
    }
    {
      f32x4 s = ac[0] + ac[1];
      #pragma unroll
      for (int r = 0; r < 4; ++r) red[w][4][ko * 4 + r][lw] = s[r];
    }
    __syncthreads();

    // ---- S3: elementwise update (thread owns (ub, uj)) ----
    {
      float gi = red[0][0][ub][uj] + red[1][0][ub][uj] + red[2][0][ub][uj] + red[3][0][ub][uj] + bs_i;
      float gf = red[0][1][ub][uj] + red[1][1][ub][uj] + red[2][1][ub][uj] + red[3][1][ub][uj] + bs_f;
      float gg = red[0][2][ub][uj] + red[1][2][ub][uj] + red[2][2][ub][uj] + red[3][2][ub][uj] + bs_g;
      float go = red[0][3][ub][uj] + red[1][3][ub][uj] + red[2][3][ub][uj] + red[3][3][ub][uj] + bs_o;
      float csv = red[0][4][ub][uj] + red[1][4][ub][uj] + red[2][4][ub][uj] + red[3][4][ub][uj] + bs_d;

      float c_s = tanh_f(csv);
      float dinv = 1.0f / __logf(2.718281828459045f + tt);
      float c_adj = c_reg - c_s + c_s * dinv;
      float iv = sigm(gi);
      float fv = sigm(gf);
      float ov = sigm(go);
      float gv = tanh_f(gg);
      float c_new = fv * c_adj + iv * gv;
      float h_new = ov * tanh_f(c_new);
      c_reg = c_new;

      short hh = f2bf(h_new), hl2 = f2bf(h_new - bf2f(hh));
      short ch = f2bf(c_new), cl2 = f2bf(c_new - bf2f(ch));
      unsigned hword = ((unsigned)(unsigned short)hh << 16) | (unsigned)(unsigned short)hl2;
      unsigned cword = ((unsigned)(unsigned short)ch << 16) | (unsigned)(unsigned short)cl2;
      u32x2 val; val[0] = hword; val[1] = cword;
      unsigned* sp = state + 2u * ((size_t)nbuf * 8192 + (size_t)ub * 512 + jglob);
      asm volatile("global_store_dwordx2 %0, %1, off sc0 sc1" :: "v"(sp), "v"(val) : "memory");
      out[((size_t)tsrc * B_DIM + b0 + ub) * 1024 + dir * 512 + jglob] = h_new;
    }

    // ---- S4: per-wave store drain, block barrier, single flag release ----
    asm volatile("s_waitcnt vmcnt(0)" ::: "memory");
    __syncthreads();
    if (tid == 0)
      __hip_atomic_store(&flags[js], t + 1, __ATOMIC_RELAXED, __HIP_MEMORY_SCOPE_AGENT);
  }
}

extern "C" void kernel_launch(void* const* d_in, const int* in_sizes, int n_in,
                              void* d_out, int out_size, void* d_ws, size_t ws_size,
                              hipStream_t stream) {
  (void)in_sizes; (void)n_in; (void)out_size;
  if (ws_size < (size_t)WS_NEED) return;  // failure signature: ws too small

  const float* x     = (const float*)d_in[0];
  const float* tim   = (const float*)d_in[1];
  const float* Wih_f = (const float*)d_in[2];
  const float* Whh_f = (const float*)d_in[3];
  const float* b_f   = (const float*)d_in[4];
  const float* Wd_f  = (const float*)d_in[5];
  const float* bd_f  = (const float*)d_in[6];
  const float* Wih_b = (const float*)d_in[7];
  const float* Whh_b = (const float*)d_in[8];
  const float* b_b   = (const float*)d_in[9];
  const float* Wd_b  = (const float*)d_in[10];
  const float* bd_b  = (const float*)d_in[11];
  float* out = (float*)d_out;
  char* ws = (char*)d_ws;

  hipLaunchKernelGGL(init_ws_kernel, dim3(64), dim3(256), 0, stream, (unsigned*)ws);
  hipLaunchKernelGGL(lstm_kernel, dim3(256), dim3(256), 0, stream,
                     x, tim, Wih_f, Whh_f, b_f, Wd_f, bd_f,
                     Wih_b, Whh_b, b_b, Wd_b, bd_b, out, ws);
}

// Round 7
// 2535.290 us; speedup vs baseline: 7.4350x; 1.0438x over previous
//
#include <hip/hip_runtime.h>
#include <cstdint>

#define T_DIM 512
#define B_DIM 64
#define I_DIM 256
#define H_DIM 512

typedef short bf16x8 __attribute__((ext_vector_type(8)));
typedef float f32x4  __attribute__((ext_vector_type(4)));
typedef unsigned int u32x4 __attribute__((ext_vector_type(4)));
typedef unsigned int u32x2 __attribute__((ext_vector_type(2)));

union BF8U { bf16x8 v; u32x4 u; };

// ---- ws layout ----
#define WS_FLAGS   0u                         // 8 groups * 2048B; flag(g,j) at g*2048 + j*64
#define WS_STATE   16384u                     // 8 groups * 131072B
#define GRP_BYTES  131072u
#define WS_XPK     (WS_STATE + 8u*GRP_BYTES)  // 1,064,960
#define XPK_UINTS  (512u*4u*8u*64u*8u)        // 8,388,608 uints = 32MB
#define WS_NEED_MIN WS_XPK
#define WS_NEED_XPK (WS_XPK + XPK_UINTS*4u)

__device__ __forceinline__ short f2bf(float f) {
  unsigned u = __float_as_uint(f);
  unsigned r = (u + 0x7FFFu + ((u >> 16) & 1u)) >> 16;  // RNE
  return (short)r;
}
__device__ __forceinline__ float bf2f(short s) {
  return __uint_as_float(((unsigned)(unsigned short)s) << 16);
}
__device__ __forceinline__ float sigm(float v) { return 1.0f / (1.0f + __expf(-v)); }
__device__ __forceinline__ float tanh_f(float v) {
  float e = __expf(2.0f * fabsf(v));
  float r = 1.0f - 2.0f / (e + 1.0f);
  return copysignf(r, v);
}

// agent-scope coherence-point accesses (PROVEN in R2/R3): sc0 sc1
__device__ __forceinline__ void st_u32(unsigned* p, unsigned v) {
  asm volatile("global_store_dword %0, %1, off sc0 sc1" :: "v"(p), "v"(v) : "memory");
}
__device__ __forceinline__ void st_u32x2(unsigned* p, u32x2 v) {
  asm volatile("global_store_dwordx2 %0, %1, off sc0 sc1" :: "v"(p), "v"(v) : "memory");
}
__device__ __forceinline__ unsigned ld_u32(const unsigned* p) {
  unsigned v;
  asm volatile("global_load_dword %0, %1, off sc0 sc1\n\ts_waitcnt vmcnt(0)"
               : "=v"(v) : "v"(p) : "memory");
  return v;
}

__global__ void __launch_bounds__(256) init_ws_kernel(unsigned* ws) {
  unsigned n = WS_NEED_MIN / 4u;
  for (unsigned i = blockIdx.x * 256u + threadIdx.x; i < n; i += gridDim.x * 256u)
    __hip_atomic_store(&ws[i], 0u, __ATOMIC_RELAXED, __HIP_MEMORY_SCOPE_AGENT);
}

// pre-pack x into per-lane MFMA fragments: [t][mt][kt(8)][lane(64)][hi x4, lo x4] uints
__global__ void __launch_bounds__(256) xpack_kernel(const float* __restrict__ x,
                                                    unsigned* __restrict__ xpk) {
  size_t idx = (size_t)blockIdx.x * 256 + threadIdx.x;   // 1,048,576 total
  int l = (int)(idx & 63);
  size_t kt = (idx >> 6) & 7, mt = (idx >> 9) & 3, t = idx >> 11;
  const float* xp = x + ((t * 64) + mt * 16 + (size_t)(l & 15)) * 256 + kt * 32 + (size_t)(l >> 4) * 8;
  f32x4 a = *(const f32x4*)xp, b = *(const f32x4*)(xp + 4);
  float v[8] = {a[0], a[1], a[2], a[3], b[0], b[1], b[2], b[3]};
  u32x4 hi, lo;
  #pragma unroll
  for (int i = 0; i < 4; ++i) {
    short h0 = f2bf(v[2 * i]), h1 = f2bf(v[2 * i + 1]);
    short l0 = f2bf(v[2 * i] - bf2f(h0)), l1 = f2bf(v[2 * i + 1] - bf2f(h1));
    hi[i] = (unsigned)(unsigned short)h0 | ((unsigned)(unsigned short)h1 << 16);
    lo[i] = (unsigned)(unsigned short)l0 | ((unsigned)(unsigned short)l1 << 16);
  }
  unsigned* dst = xpk + idx * 8;
  *(u32x4*)dst = hi;
  *(u32x4*)(dst + 4) = lo;
}

// 256 blocks x 256 threads (PROVEN R3 geometry). Group g = blockIdx&7, 32 blocks/group,
// block owns 16 output cols (js = blockIdx>>3). Wave w: x k=[64w,64w+64),
// h/c k=[128w,128w+128). All cross-block traffic agent-scope sc0|sc1.
template <bool XPK>
__global__ void __launch_bounds__(256, 1) lstm_kernel(
    const float* __restrict__ x, const float* __restrict__ tim,
    const float* __restrict__ Wih_f, const float* __restrict__ Whh_f,
    const float* __restrict__ bias_f, const float* __restrict__ Wd_f,
    const float* __restrict__ bd_f,
    const float* __restrict__ Wih_b, const float* __restrict__ Whh_b,
    const float* __restrict__ bias_b, const float* __restrict__ Wd_b,
    const float* __restrict__ bd_b,
    float* __restrict__ out, char* __restrict__ wsb,
    const unsigned* __restrict__ xpk)
{
  const int tid = threadIdx.x;
  const int w   = tid >> 6;
  const int l   = tid & 63;
  const int lw  = l & 15;
  const int ko  = l >> 4;
  const int g   = blockIdx.x & 7;
  const int js  = blockIdx.x >> 3;        // 0..31
  const int dir = g & 1;
  const int mt  = g >> 1;
  const int b0  = mt * 16;

  const float* Wih  = dir ? Wih_b  : Wih_f;
  const float* Whh  = dir ? Whh_b  : Whh_f;
  const float* bias = dir ? bias_b : bias_f;
  const float* Wd   = dir ? Wd_b   : Wd_f;
  const float* bd   = dir ? bd_b   : bd_f;

  unsigned* flagbase = (unsigned*)(wsb + WS_FLAGS) + (size_t)g * 512;  // 2048B/group, 64B/flag
  unsigned* state = (unsigned*)(wsb + WS_STATE) + (size_t)g * (GRP_BYTES / 4);
  // state: uint2[buf][batch(16)][k(512)] = (h_hi<<16|h_lo , c_hi<<16|c_lo)

  __shared__ float red[4][5][16][18];

  // ---- weight preload (hi/lo bf16 split), persists all 512 steps ----
  bf16x8 wxh[4][2], wxl[4][2];
  bf16x8 whh[4][4], whl[4][4];
  bf16x8 wdh[4],    wdl[4];
  #pragma unroll
  for (int xi = 0; xi < 2; ++xi) {
    const int krow = (w * 2 + xi) * 32 + ko * 8;
    #pragma unroll
    for (int g4 = 0; g4 < 4; ++g4) {
      const float* p = Wih + (size_t)krow * 2048 + g4 * 512 + js * 16 + lw;
      #pragma unroll
      for (int i = 0; i < 8; ++i) {
        float v = p[(size_t)i * 2048];
        short hi = f2bf(v);
        wxh[g4][xi][i] = hi;
        wxl[g4][xi][i] = f2bf(v - bf2f(hi));
      }
    }
  }
  #pragma unroll
  for (int q = 0; q < 4; ++q) {
    const int krow = w * 128 + q * 32 + ko * 8;
    #pragma unroll
    for (int g4 = 0; g4 < 4; ++g4) {
      const float* p = Whh + (size_t)krow * 2048 + g4 * 512 + js * 16 + lw;
      #pragma unroll
      for (int i = 0; i < 8; ++i) {
        float v = p[(size_t)i * 2048];
        short hi = f2bf(v);
        whh[g4][q][i] = hi;
        whl[g4][q][i] = f2bf(v - bf2f(hi));
      }
    }
    const float* p2 = Wd + (size_t)krow * 512 + js * 16 + lw;
    #pragma unroll
    for (int i = 0; i < 8; ++i) {
      float v = p2[(size_t)i * 512];
      short hi = f2bf(v);
      wdh[q][i] = hi;
      wdl[q][i] = f2bf(v - bf2f(hi));
    }
  }

  const int ub = tid >> 4;
  const int uj = tid & 15;
  const int jglob = js * 16 + uj;
  const float bs_i = bias[jglob];
  const float bs_f = bias[512 + jglob];
  const float bs_g = bias[1024 + jglob];
  const float bs_o = bias[1536 + jglob];
  const float bs_d = bd[jglob];
  float c_reg = 0.0f;

  for (int t = 0; t < T_DIM; ++t) {
    const int tsrc = dir ? (T_DIM - 1 - t) : t;
    const int buf = t & 1;
    const int nbuf = buf ^ 1;

    // ---- X phase (independent of t-1 state; overlaps straggler wait) ----
    f32x4 ag[4][2]; f32x4 ac[2];
    #pragma unroll
    for (int g4 = 0; g4 < 4; ++g4) { ag[g4][0] = (f32x4)0.0f; ag[g4][1] = (f32x4)0.0f; }
    ac[0] = (f32x4)0.0f; ac[1] = (f32x4)0.0f;

    float tt = tim[(size_t)tsrc * B_DIM + b0 + ub];

    bf16x8 axh[2], axl[2];
    if (XPK) {
      const unsigned* xb = xpk + ((((size_t)tsrc * 4 + mt) * 8 + w * 2) * 64 + l) * 8;
      BF8U h0, l0, h1, l1;
      h0.u = *(const u32x4*)xb;         l0.u = *(const u32x4*)(xb + 4);
      h1.u = *(const u32x4*)(xb + 512); l1.u = *(const u32x4*)(xb + 516);
      axh[0] = h0.v; axl[0] = l0.v; axh[1] = h1.v; axl[1] = l1.v;
    } else {
      #pragma unroll
      for (int xi = 0; xi < 2; ++xi) {
        const float* xp = x + ((size_t)tsrc * B_DIM + b0 + lw) * I_DIM + (w * 2 + xi) * 32 + ko * 8;
        f32x4 v0 = *(const f32x4*)xp;
        f32x4 v1 = *(const f32x4*)(xp + 4);
        bf16x8 vh, vl;
        #pragma unroll
        for (int i = 0; i < 4; ++i) {
          short h0 = f2bf(v0[i]); vh[i] = h0;     vl[i] = f2bf(v0[i] - bf2f(h0));
          short h1 = f2bf(v1[i]); vh[4 + i] = h1; vl[4 + i] = f2bf(v1[i] - bf2f(h1));
        }
        axh[xi] = vh; axl[xi] = vl;
      }
    }
    #pragma unroll
    for (int xi = 0; xi < 2; ++xi) {
      #pragma unroll
      for (int g4 = 0; g4 < 4; ++g4) {
        f32x4 acc = ag[g4][xi];
        acc = __builtin_amdgcn_mfma_f32_16x16x32_bf16(axh[xi], wxh[g4][xi], acc, 0, 0, 0);
        acc = __builtin_amdgcn_mfma_f32_16x16x32_bf16(axl[xi], wxh[g4][xi], acc, 0, 0, 0);
        acc = __builtin_amdgcn_mfma_f32_16x16x32_bf16(axh[xi], wxl[g4][xi], acc, 0, 0, 0);
        ag[g4][xi] = acc;
      }
    }

    // ---- W0: wait for all 32 producer flags (parallel lanes, 64B-strided) ----
    if (t > 0) {
      if (l < 32) {
        const unsigned* fl = flagbase + (size_t)l * 16;
        while (ld_u32(fl) < (unsigned)t) { }
      }
      __builtin_amdgcn_sched_barrier(0);
    } else {
      asm volatile("s_waitcnt vmcnt(0)" ::: "memory");
    }

    // ---- S1: issue all 16 state loads (h,c interleaved uint2) ----
    u32x4 rr[4][4];
    #pragma unroll
    for (int q = 0; q < 4; ++q) {
      const unsigned* sp = state + 2u * ((size_t)buf * 8192 + (size_t)lw * 512 + w * 128 + q * 32 + ko * 8);
      asm volatile(
          "global_load_dwordx4 %0, %4, off sc0 sc1\n\t"
          "global_load_dwordx4 %1, %4, off offset:16 sc0 sc1\n\t"
          "global_load_dwordx4 %2, %4, off offset:32 sc0 sc1\n\t"
          "global_load_dwordx4 %3, %4, off offset:48 sc0 sc1"
          : "=v"(rr[q][0]), "=v"(rr[q][1]), "=v"(rr[q][2]), "=v"(rr[q][3])
          : "v"(sp) : "memory");
    }

    // ---- S2: per-q counted wait -> unpack (v_perm) -> MFMAs (overlap with loads) ----
    #pragma unroll
    for (int q = 0; q < 4; ++q) {
      if (q == 0)      asm volatile("s_waitcnt vmcnt(12)" ::: "memory");
      else if (q == 1) asm volatile("s_waitcnt vmcnt(8)" ::: "memory");
      else if (q == 2) asm volatile("s_waitcnt vmcnt(4)" ::: "memory");
      else             asm volatile("s_waitcnt vmcnt(0)" ::: "memory");
      __builtin_amdgcn_sched_barrier(0);

      BF8U hh_, hl_, ch_, cl_;
      #pragma unroll
      for (int j = 0; j < 4; ++j) {
        unsigned hw0 = rr[q][j][0], cw0 = rr[q][j][1];
        unsigned hw1 = rr[q][j][2], cw1 = rr[q][j][3];
        hh_.u[j] = __builtin_amdgcn_perm(hw1, hw0, 0x07060302u);
        hl_.u[j] = __builtin_amdgcn_perm(hw1, hw0, 0x05040100u);
        ch_.u[j] = __builtin_amdgcn_perm(cw1, cw0, 0x07060302u);
        cl_.u[j] = __builtin_amdgcn_perm(cw1, cw0, 0x05040100u);
      }
      #pragma unroll
      for (int g4 = 0; g4 < 4; ++g4) {
        f32x4 acc = ag[g4][q & 1];
        acc = __builtin_amdgcn_mfma_f32_16x16x32_bf16(hh_.v, whh[g4][q], acc, 0, 0, 0);
        acc = __builtin_amdgcn_mfma_f32_16x16x32_bf16(hl_.v, whh[g4][q], acc, 0, 0, 0);
        acc = __builtin_amdgcn_mfma_f32_16x16x32_bf16(hh_.v, whl[g4][q], acc, 0, 0, 0);
        ag[g4][q & 1] = acc;
      }
      f32x4 a2 = ac[q & 1];
      a2 = __builtin_amdgcn_mfma_f32_16x16x32_bf16(ch_.v, wdh[q], a2, 0, 0, 0);
      a2 = __builtin_amdgcn_mfma_f32_16x16x32_bf16(cl_.v, wdh[q], a2, 0, 0, 0);
      a2 = __builtin_amdgcn_mfma_f32_16x16x32_bf16(ch_.v, wdl[q], a2, 0, 0, 0);
      ac[q & 1] = a2;
    }

    // ---- S2b: deterministic cross-wave reduce via LDS ----
    #pragma unroll
    for (int g4 = 0; g4 < 4; ++g4) {
      f32x4 s = ag[g4][0] + ag[g4][1];
      #pragma unroll
      for (int r = 0; r < 4; ++r) red[w][g4][ko * 4 + r][lw] = s[r];
    }
    {
      f32x4 s = ac[0] + ac[1];
      #pragma unroll
      for (int r = 0; r < 4; ++r) red[w][4][ko * 4 + r][lw] = s[r];
    }
    __syncthreads();

    // ---- S3: elementwise update (state store only; out deferred past release) ----
    float h_keep;
    {
      float gi = red[0][0][ub][uj] + red[1][0][ub][uj] + red[2][0][ub][uj] + red[3][0][ub][uj] + bs_i;
      float gf = red[0][1][ub][uj] + red[1][1][ub][uj] + red[2][1][ub][uj] + red[3][1][ub][uj] + bs_f;
      float gg = red[0][2][ub][uj] + red[1][2][ub][uj] + red[2][2][ub][uj] + red[3][2][ub][uj] + bs_g;
      float go = red[0][3][ub][uj] + red[1][3][ub][uj] + red[2][3][ub][uj] + red[3][3][ub][uj] + bs_o;
      float csv = red[0][4][ub][uj] + red[1][4][ub][uj] + red[2][4][ub][uj] + red[3][4][ub][uj] + bs_d;

      float c_s = tanh_f(csv);
      float dinv = 1.0f / __logf(2.718281828459045f + tt);
      float c_adj = c_reg - c_s + c_s * dinv;
      float iv = sigm(gi);
      float fv = sigm(gf);
      float ov = sigm(go);
      float gv = tanh_f(gg);
      float c_new = fv * c_adj + iv * gv;
      float h_new = ov * tanh_f(c_new);
      c_reg = c_new;
      h_keep = h_new;

      short hh = f2bf(h_new), hl2 = f2bf(h_new - bf2f(hh));
      short ch = f2bf(c_new), cl2 = f2bf(c_new - bf2f(ch));
      u32x2 val;
      val[0] = ((unsigned)(unsigned short)hh << 16) | (unsigned)(unsigned short)hl2;
      val[1] = ((unsigned)(unsigned short)ch << 16) | (unsigned)(unsigned short)cl2;
      unsigned* sp = state + 2u * ((size_t)nbuf * 8192 + (size_t)ub * 512 + jglob);
      st_u32x2(sp, val);
    }

    // ---- S4: drain state stores, barrier, release flag, THEN out store ----
    asm volatile("s_waitcnt vmcnt(0)" ::: "memory");
    __syncthreads();
    if (tid == 0) st_u32(flagbase + (size_t)js * 16, (unsigned)(t + 1));
    out[((size_t)tsrc * B_DIM + b0 + ub) * 1024 + dir * 512 + jglob] = h_keep;
  }
}

extern "C" void kernel_launch(void* const* d_in, const int* in_sizes, int n_in,
                              void* d_out, int out_size, void* d_ws, size_t ws_size,
                              hipStream_t stream) {
  (void)in_sizes; (void)n_in; (void)out_size;
  if (ws_size < (size_t)WS_NEED_MIN) return;  // failure signature: ws too small
  const bool use_xpk = ws_size >= (size_t)WS_NEED_XPK;

  const float* x     = (const float*)d_in[0];
  const float* tim   = (const float*)d_in[1];
  const float* Wih_f = (const float*)d_in[2];
  const float* Whh_f = (const float*)d_in[3];
  const float* b_f   = (const float*)d_in[4];
  const float* Wd_f  = (const float*)d_in[5];
  const float* bd_f  = (const float*)d_in[6];
  const float* Wih_b = (const float*)d_in[7];
  const float* Whh_b = (const float*)d_in[8];
  const float* b_b   = (const float*)d_in[9];
  const float* Wd_b  = (const float*)d_in[10];
  const float* bd_b  = (const float*)d_in[11];
  float* out = (float*)d_out;
  char* ws = (char*)d_ws;
  unsigned* xpk = (unsigned*)(ws + WS_XPK);

  hipLaunchKernelGGL(init_ws_kernel, dim3(64), dim3(256), 0, stream, (unsigned*)ws);
  if (use_xpk) {
    hipLaunchKernelGGL(xpack_kernel, dim3(4096), dim3(256), 0, stream, x, xpk);
    hipLaunchKernelGGL((lstm_kernel<true>), dim3(256), dim3(256), 0, stream,
                       x, tim, Wih_f, Whh_f, b_f, Wd_f, bd_f,
                       Wih_b, Whh_b, b_b, Wd_b, bd_b, out, ws, xpk);
  } else {
    hipLaunchKernelGGL((lstm_kernel<false>), dim3(256), dim3(256), 0, stream,
                       x, tim, Wih_f, Whh_f, b_f, Wd_f, bd_f,
                       Wih_b, Whh_b, b_b, Wd_b, bd_b, out, ws, (const unsigned*)nullptr);
  }
}